// Round 4
// baseline (167.228 us; speedup 1.0000x reference)
//
#include <hip/hip_runtime.h>

#define NN 131072
#define WW 256

typedef float f32x4 __attribute__((ext_vector_type(4)));

__device__ __forceinline__ float clamp01f(float x) { return fminf(fmaxf(x, 0.0f), 1.0f); }

__device__ __forceinline__ float wave_reduce_sum(float v) {
#pragma unroll
    for (int m = 1; m < 64; m <<= 1) v += __shfl_xor(v, m, 64);
    return v;
}

// ---- kernel 1: exp_t[i] = exp(beta * cos(mem[i], key_c)); per-block partial sums -> p1
__global__ __launch_bounds__(256) void k_content(const float* __restrict__ mem,
                                                 const float* __restrict__ key,
                                                 const float* __restrict__ beta_p,
                                                 float* __restrict__ exp_t,
                                                 float* __restrict__ p1) {
    const int tid  = threadIdx.x;
    const int lane = tid & 63;
    const int wv   = tid >> 6;
    const int wid  = (blockIdx.x << 2) + wv;   // 8192 waves total
    const float beta = beta_p[0];

    float4 k4 = reinterpret_cast<const float4*>(key)[lane];
    k4.x = clamp01f(k4.x); k4.y = clamp01f(k4.y);
    k4.z = clamp01f(k4.z); k4.w = clamp01f(k4.w);
    float ksq = wave_reduce_sum(k4.x * k4.x + k4.y * k4.y + k4.z * k4.z + k4.w * k4.w);
    const float inv_kn = 1.0f / sqrtf(ksq);

    float local = 0.0f;
    for (int row = wid; row < NN; row += 8192) {
        float4 m = reinterpret_cast<const float4*>(mem)[row * 64 + lane];
        float dot = m.x * k4.x + m.y * k4.y + m.z * k4.z + m.w * k4.w;
        float ssq = m.x * m.x + m.y * m.y + m.z * m.z + m.w * m.w;
        dot = wave_reduce_sum(dot);
        ssq = wave_reduce_sum(ssq);
        if (lane == 0) {
            float t = expf(beta * dot * inv_kn / sqrtf(ssq));
            exp_t[row] = t;
            local += t;
        }
    }
    __shared__ float sb[4];
    if (lane == 0) sb[wv] = local;
    __syncthreads();
    if (tid == 0) p1[blockIdx.x] = (sb[0] + sb[1]) + (sb[2] + sb[3]);
}

// ---- kernel 2 (fused): S1 = sum(p1); wg on-the-fly; circular shift; pow; partials -> p2
//      Also zeroes the ticket counters used by kernel 3 (block 0).
__global__ __launch_bounds__(256) void k_shift_pow(const float* __restrict__ exp_t,
                                                   const float* __restrict__ w_prev,
                                                   const float* __restrict__ p1,
                                                   const float* __restrict__ gate_p,
                                                   const float* __restrict__ shift,
                                                   const float* __restrict__ gamma_p,
                                                   float* __restrict__ wlp,
                                                   float* __restrict__ p2,
                                                   unsigned int* __restrict__ cnt) {
    __shared__ float red[256];
    const int tid = threadIdx.x;
    if (blockIdx.x == 0 && tid < 64) cnt[tid] = 0u;   // 32 group counters + 1 final
    // S1 reduction (every block, 8 KB L2-hit)
    float s = 0.0f;
#pragma unroll
    for (int k = 0; k < 8; ++k) s += p1[tid + 256 * k];
    red[tid] = s;
    __syncthreads();
    for (int st = 128; st > 0; st >>= 1) {
        if (tid < st) red[tid] += red[tid + st];
        __syncthreads();
    }
    const float invS1 = 1.0f / red[0];
    __syncthreads();

    const float g  = gate_p[0];
    const float s0 = clamp01f(shift[0]);
    const float s1 = clamp01f(shift[1]);
    const float s2 = clamp01f(shift[2]);
    const float gmm = gamma_p[0];
    const int i = blockIdx.x * 256 + tid;

    const int ip = (i + 1) & (NN - 1);
    const int im = (i + NN - 1) & (NN - 1);
    const float wg_p = g * (exp_t[ip] * invS1) + (1.0f - g) * clamp01f(w_prev[ip]);
    const float wg_c = g * (exp_t[i]  * invS1) + (1.0f - g) * clamp01f(w_prev[i]);
    const float wg_m = g * (exp_t[im] * invS1) + (1.0f - g) * clamp01f(w_prev[im]);
    const float wl = s0 * wg_p + s1 * wg_c + s2 * wg_m;
    const float v  = powf(wl, gmm);
    wlp[i] = v;

    red[tid] = v;
    __syncthreads();
    for (int st = 128; st > 0; st >>= 1) {
        if (tid < st) red[tid] += red[tid + st];
        __syncthreads();
    }
    if (tid == 0) p2[blockIdx.x] = red[0];
}

// ---- kernel 3 (fused): S2; w out; erase+add; r partials; in-kernel ticketed r-reduction
__global__ __launch_bounds__(256) void k_update(const float* __restrict__ mem,
                                                const float* __restrict__ wlp,
                                                const float* __restrict__ p2,
                                                const float* __restrict__ e,
                                                const float* __restrict__ a,
                                                float* __restrict__ out_mem,
                                                float* __restrict__ out_w,
                                                float* __restrict__ rp,
                                                float* __restrict__ rp2,
                                                float* __restrict__ out_r,
                                                unsigned int* __restrict__ cnt) {
    __shared__ float lds[4 * 256];
    __shared__ unsigned int flag;
    const int tid  = threadIdx.x;
    const int lane = tid & 63;
    const int wv   = tid >> 6;
    const int wid  = (blockIdx.x << 2) + wv;

    // S2 reduction (every block, 2 KB L2-hit)
    lds[tid] = p2[tid] + p2[tid + 256];
    __syncthreads();
    for (int st = 128; st > 0; st >>= 1) {
        if (tid < st) lds[tid] += lds[tid + st];
        __syncthreads();
    }
    const float invS2 = 1.0f / lds[0];
    __syncthreads();

    // coalesced w output: block b writes rows [b*64, b*64+64)
    if (tid < 64) {
        const int row = blockIdx.x * 64 + tid;
        out_w[row] = wlp[row] * invS2;
    }

    float4 e4 = reinterpret_cast<const float4*>(e)[lane];
    e4.x = clamp01f(e4.x); e4.y = clamp01f(e4.y);
    e4.z = clamp01f(e4.z); e4.w = clamp01f(e4.w);
    float4 a4 = reinterpret_cast<const float4*>(a)[lane];
    a4.x = clamp01f(a4.x); a4.y = clamp01f(a4.y);
    a4.z = clamp01f(a4.z); a4.w = clamp01f(a4.w);

    float4 racc = make_float4(0.0f, 0.0f, 0.0f, 0.0f);
    for (int row = wid; row < NN; row += 8192) {
        const float wr = clamp01f(wlp[row] * invS2);   // broadcast read
        float4 m = reinterpret_cast<const float4*>(mem)[row * 64 + lane];
        f32x4 nm;
        nm.x = m.x * (1.0f - wr * e4.x) + wr * a4.x;
        nm.y = m.y * (1.0f - wr * e4.y) + wr * a4.y;
        nm.z = m.z * (1.0f - wr * e4.z) + wr * a4.z;
        nm.w = m.w * (1.0f - wr * e4.w) + wr * a4.w;
        __builtin_nontemporal_store(nm, reinterpret_cast<f32x4*>(out_mem) + row * 64 + lane);
        racc.x += wr * m.x;
        racc.y += wr * m.y;
        racc.z += wr * m.z;
        racc.w += wr * m.w;
    }
    reinterpret_cast<float4*>(lds)[wv * 64 + lane] = racc;
    __syncthreads();
    const float s = lds[0 * 256 + tid] + lds[1 * 256 + tid] + lds[2 * 256 + tid] + lds[3 * 256 + tid];
    rp[blockIdx.x * 256 + tid] = s;

    // ---- ticketed tail reduction (deterministic: fixed-order sums, any executor) ----
    const int g = blockIdx.x >> 6;   // group of 64 blocks
    __syncthreads();                 // all rp writes of this block done
    if (tid == 0) {
        __threadfence();             // release rp row
        flag = (atomicAdd(&cnt[g], 1u) == 63u);
    }
    __syncthreads();
    if (flag) {
        __threadfence();             // acquire: all 64 rp rows of group g visible
        float s1 = 0.0f;
        for (int k = 0; k < 64; ++k) s1 += rp[(g * 64 + k) * 256 + tid];
        rp2[g * 256 + tid] = s1;
        __syncthreads();
        if (tid == 0) {
            __threadfence();         // release rp2 row
            flag = (atomicAdd(&cnt[32], 1u) == 31u);
        }
        __syncthreads();
        if (flag) {
            __threadfence();         // acquire: all rp2 rows visible
            float s2 = 0.0f;
            for (int b = 0; b < 32; ++b) s2 += rp2[b * 256 + tid];
            out_r[tid] = s2;
        }
    }
}

extern "C" void kernel_launch(void* const* d_in, const int* in_sizes, int n_in,
                              void* d_out, int out_size, void* d_ws, size_t ws_size,
                              hipStream_t stream) {
    const float* mem    = (const float*)d_in[0];
    const float* key    = (const float*)d_in[1];
    const float* beta_p = (const float*)d_in[2];
    const float* gamma_p= (const float*)d_in[3];
    const float* gate_p = (const float*)d_in[4];
    const float* shift  = (const float*)d_in[5];
    const float* w_prev = (const float*)d_in[6];
    const float* e      = (const float*)d_in[7];
    const float* a      = (const float*)d_in[8];

    float* out   = (float*)d_out;
    float* out_r = out;                        // [256]
    float* out_m = out + WW;                   // [131072*256]
    float* out_w = out + WW + (size_t)NN * WW; // [131072]

    float* ws = (float*)d_ws;
    float* exp_t = ws;                         // N
    float* wlp   = ws + NN;                    // N
    float* p1    = ws + 2 * NN;                // 2048
    float* p2    = p1 + 2048;                  // 512
    float* rp    = p2 + 512;                   // 2048*256
    float* rp2   = rp + 2048 * 256;            // 32*256
    unsigned int* cnt = (unsigned int*)(rp2 + 32 * 256); // 64 counters

    k_content<<<2048, 256, 0, stream>>>(mem, key, beta_p, exp_t, p1);
    k_shift_pow<<<512, 256, 0, stream>>>(exp_t, w_prev, p1, gate_p, shift, gamma_p, wlp, p2, cnt);
    k_update<<<2048, 256, 0, stream>>>(mem, wlp, p2, e, a, out_m, out_w, rp, rp2, out_r, cnt);
}

// Round 5
// 79.282 us; speedup vs baseline: 2.1093x; 2.1093x over previous
//
#include <hip/hip_runtime.h>

#define NN 131072
#define WW 256

typedef float f32x4 __attribute__((ext_vector_type(4)));

__device__ __forceinline__ float clamp01f(float x) { return fminf(fmaxf(x, 0.0f), 1.0f); }

__device__ __forceinline__ float wave_reduce_sum(float v) {
#pragma unroll
    for (int m = 1; m < 64; m <<= 1) v += __shfl_xor(v, m, 64);
    return v;
}

// ---- kernel 1: exp_t[i] = exp(beta * cos(mem[i], key_c)); per-block partial sums -> p1
__global__ __launch_bounds__(256) void k_content(const float* __restrict__ mem,
                                                 const float* __restrict__ key,
                                                 const float* __restrict__ beta_p,
                                                 float* __restrict__ exp_t,
                                                 float* __restrict__ p1) {
    const int tid  = threadIdx.x;
    const int lane = tid & 63;
    const int wv   = tid >> 6;
    const int wid  = (blockIdx.x << 2) + wv;   // 8192 waves total
    const float beta = beta_p[0];

    float4 k4 = reinterpret_cast<const float4*>(key)[lane];
    k4.x = clamp01f(k4.x); k4.y = clamp01f(k4.y);
    k4.z = clamp01f(k4.z); k4.w = clamp01f(k4.w);
    float ksq = wave_reduce_sum(k4.x * k4.x + k4.y * k4.y + k4.z * k4.z + k4.w * k4.w);
    const float inv_kn = 1.0f / sqrtf(ksq);

    float local = 0.0f;
    for (int row = wid; row < NN; row += 8192) {
        float4 m = reinterpret_cast<const float4*>(mem)[row * 64 + lane];
        float dot = m.x * k4.x + m.y * k4.y + m.z * k4.z + m.w * k4.w;
        float ssq = m.x * m.x + m.y * m.y + m.z * m.z + m.w * m.w;
        dot = wave_reduce_sum(dot);
        ssq = wave_reduce_sum(ssq);
        if (lane == 0) {
            float t = expf(beta * dot * inv_kn / sqrtf(ssq));
            exp_t[row] = t;
            local += t;
        }
    }
    __shared__ float sb[4];
    if (lane == 0) sb[wv] = local;
    __syncthreads();
    if (tid == 0) p1[blockIdx.x] = (sb[0] + sb[1]) + (sb[2] + sb[3]);
}

// ---- kernel 2 (fused): S1 = sum(p1); wg on-the-fly; circular shift; pow; partials -> p2
__global__ __launch_bounds__(256) void k_shift_pow(const float* __restrict__ exp_t,
                                                   const float* __restrict__ w_prev,
                                                   const float* __restrict__ p1,
                                                   const float* __restrict__ gate_p,
                                                   const float* __restrict__ shift,
                                                   const float* __restrict__ gamma_p,
                                                   float* __restrict__ wlp,
                                                   float* __restrict__ p2) {
    __shared__ float red[256];
    const int tid = threadIdx.x;
    // S1 reduction (every block, 8 KB L2-hit)
    float s = 0.0f;
#pragma unroll
    for (int k = 0; k < 8; ++k) s += p1[tid + 256 * k];
    red[tid] = s;
    __syncthreads();
    for (int st = 128; st > 0; st >>= 1) {
        if (tid < st) red[tid] += red[tid + st];
        __syncthreads();
    }
    const float invS1 = 1.0f / red[0];
    __syncthreads();

    const float g  = gate_p[0];
    const float s0 = clamp01f(shift[0]);
    const float s1 = clamp01f(shift[1]);
    const float s2 = clamp01f(shift[2]);
    const float gmm = gamma_p[0];
    const int i = blockIdx.x * 256 + tid;

    const int ip = (i + 1) & (NN - 1);
    const int im = (i + NN - 1) & (NN - 1);
    const float wg_p = g * (exp_t[ip] * invS1) + (1.0f - g) * clamp01f(w_prev[ip]);
    const float wg_c = g * (exp_t[i]  * invS1) + (1.0f - g) * clamp01f(w_prev[i]);
    const float wg_m = g * (exp_t[im] * invS1) + (1.0f - g) * clamp01f(w_prev[im]);
    const float wl = s0 * wg_p + s1 * wg_c + s2 * wg_m;
    const float v  = powf(wl, gmm);
    wlp[i] = v;

    red[tid] = v;
    __syncthreads();
    for (int st = 128; st > 0; st >>= 1) {
        if (tid < st) red[tid] += red[tid + st];
        __syncthreads();
    }
    if (tid == 0) p2[blockIdx.x] = red[0];
}

// ---- kernel 3 (fused): S2; w out; erase+add; r partials. Block b owns 64 consecutive rows.
__global__ __launch_bounds__(256) void k_update(const float* __restrict__ mem,
                                                const float* __restrict__ wlp,
                                                const float* __restrict__ p2,
                                                const float* __restrict__ e,
                                                const float* __restrict__ a,
                                                float* __restrict__ out_mem,
                                                float* __restrict__ out_w,
                                                float* __restrict__ rp) {
    __shared__ float lds[4 * 256];
    const int tid  = threadIdx.x;
    const int lane = tid & 63;
    const int wv   = tid >> 6;

    // S2 reduction (every block, 2 KB L2-hit)
    lds[tid] = p2[tid] + p2[tid + 256];
    __syncthreads();
    for (int st = 128; st > 0; st >>= 1) {
        if (tid < st) lds[tid] += lds[tid + st];
        __syncthreads();
    }
    const float invS2 = 1.0f / lds[0];
    __syncthreads();

    // coalesced w output: block b writes rows [b*64, b*64+64)
    const int b0 = blockIdx.x * 64;
    if (tid < 64) out_w[b0 + tid] = wlp[b0 + tid] * invS2;

    float4 e4 = reinterpret_cast<const float4*>(e)[lane];
    e4.x = clamp01f(e4.x); e4.y = clamp01f(e4.y);
    e4.z = clamp01f(e4.z); e4.w = clamp01f(e4.w);
    float4 a4 = reinterpret_cast<const float4*>(a)[lane];
    a4.x = clamp01f(a4.x); a4.y = clamp01f(a4.y);
    a4.z = clamp01f(a4.z); a4.w = clamp01f(a4.w);

    // wave wv owns 16 consecutive rows starting at r0
    const int r0 = b0 + wv * 16;
    // one coalesced 64B load of the 16 wlp values for this wave
    float wl16 = (lane < 16) ? wlp[r0 + lane] : 0.0f;

    float4 racc = make_float4(0.0f, 0.0f, 0.0f, 0.0f);
#pragma unroll
    for (int k = 0; k < 16; ++k) {
        const float wr = clamp01f(__shfl(wl16, k) * invS2);
        const int row = r0 + k;
        float4 m = reinterpret_cast<const float4*>(mem)[row * 64 + lane];
        f32x4 nm;
        nm.x = m.x * (1.0f - wr * e4.x) + wr * a4.x;
        nm.y = m.y * (1.0f - wr * e4.y) + wr * a4.y;
        nm.z = m.z * (1.0f - wr * e4.z) + wr * a4.z;
        nm.w = m.w * (1.0f - wr * e4.w) + wr * a4.w;
        __builtin_nontemporal_store(nm, reinterpret_cast<f32x4*>(out_mem) + row * 64 + lane);
        racc.x += wr * m.x;
        racc.y += wr * m.y;
        racc.z += wr * m.z;
        racc.w += wr * m.w;
    }
    reinterpret_cast<float4*>(lds)[wv * 64 + lane] = racc;
    __syncthreads();
    const float s = lds[0 * 256 + tid] + lds[1 * 256 + tid] + lds[2 * 256 + tid] + lds[3 * 256 + tid];
    rp[blockIdx.x * 256 + tid] = s;
}

// ---- r reduction stage 1: 32 blocks, block b sums partial rows [b*64, b*64+64)
__global__ __launch_bounds__(256) void k_rstage(const float* __restrict__ rp,
                                                float* __restrict__ rp2) {
    const int tid = threadIdx.x;
    const int b   = blockIdx.x;
    float s = 0.0f;
    for (int k = 0; k < 64; ++k) s += rp[(b * 64 + k) * 256 + tid];
    rp2[b * 256 + tid] = s;
}

// ---- r reduction stage 2: final r[256]
__global__ __launch_bounds__(256) void k_rfinal(const float* __restrict__ rp2,
                                                float* __restrict__ out_r) {
    const int tid = threadIdx.x;
    float s = 0.0f;
    for (int b = 0; b < 32; ++b) s += rp2[b * 256 + tid];
    out_r[tid] = s;
}

extern "C" void kernel_launch(void* const* d_in, const int* in_sizes, int n_in,
                              void* d_out, int out_size, void* d_ws, size_t ws_size,
                              hipStream_t stream) {
    const float* mem    = (const float*)d_in[0];
    const float* key    = (const float*)d_in[1];
    const float* beta_p = (const float*)d_in[2];
    const float* gamma_p= (const float*)d_in[3];
    const float* gate_p = (const float*)d_in[4];
    const float* shift  = (const float*)d_in[5];
    const float* w_prev = (const float*)d_in[6];
    const float* e      = (const float*)d_in[7];
    const float* a      = (const float*)d_in[8];

    float* out   = (float*)d_out;
    float* out_r = out;                        // [256]
    float* out_m = out + WW;                   // [131072*256]
    float* out_w = out + WW + (size_t)NN * WW; // [131072]

    float* ws = (float*)d_ws;
    float* exp_t = ws;                         // N
    float* wlp   = ws + NN;                    // N
    float* p1    = ws + 2 * NN;                // 2048
    float* p2    = p1 + 2048;                  // 512
    float* rp    = p2 + 512;                   // 2048*256
    float* rp2   = rp + 2048 * 256;            // 32*256

    k_content<<<2048, 256, 0, stream>>>(mem, key, beta_p, exp_t, p1);
    k_shift_pow<<<512, 256, 0, stream>>>(exp_t, w_prev, p1, gate_p, shift, gamma_p, wlp, p2);
    k_update<<<2048, 256, 0, stream>>>(mem, wlp, p2, e, a, out_m, out_w, rp);
    k_rstage<<<32, 256, 0, stream>>>(rp, rp2);
    k_rfinal<<<1, 256, 0, stream>>>(rp2, out_r);
}

// Round 7
// 78.030 us; speedup vs baseline: 2.1431x; 1.0160x over previous
//
#include <hip/hip_runtime.h>

#define NN 131072
#define WW 256

typedef float f32x4 __attribute__((ext_vector_type(4)));
typedef _Float16 f16x4 __attribute__((ext_vector_type(4)));

__device__ __forceinline__ float clamp01f(float x) { return fminf(fmaxf(x, 0.0f), 1.0f); }

__device__ __forceinline__ float wave_reduce_sum(float v) {
#pragma unroll
    for (int m = 1; m < 64; m <<= 1) v += __shfl_xor(v, m, 64);
    return v;
}

// ---- kernel 1: exp_t[i] = exp(beta*cos(mem[i],key_c)); partial sums -> p1;
//      optionally writes fp16 shadow copy of mem for k_update's replay read.
__global__ __launch_bounds__(256) void k_content(const float* __restrict__ mem,
                                                 const float* __restrict__ key,
                                                 const float* __restrict__ beta_p,
                                                 float* __restrict__ exp_t,
                                                 float* __restrict__ p1,
                                                 f16x4* __restrict__ mem16,
                                                 int use16) {
    const int tid  = threadIdx.x;
    const int lane = tid & 63;
    const int wv   = tid >> 6;
    const int wid  = (blockIdx.x << 2) + wv;   // 8192 waves total
    const float beta = beta_p[0];

    float4 k4 = reinterpret_cast<const float4*>(key)[lane];
    k4.x = clamp01f(k4.x); k4.y = clamp01f(k4.y);
    k4.z = clamp01f(k4.z); k4.w = clamp01f(k4.w);
    float ksq = wave_reduce_sum(k4.x * k4.x + k4.y * k4.y + k4.z * k4.z + k4.w * k4.w);
    const float inv_kn = 1.0f / sqrtf(ksq);

    float local = 0.0f;
    for (int row = wid; row < NN; row += 8192) {
        float4 m = reinterpret_cast<const float4*>(mem)[row * 64 + lane];
        if (use16) {
            f16x4 h;
            h.x = (_Float16)m.x; h.y = (_Float16)m.y;
            h.z = (_Float16)m.z; h.w = (_Float16)m.w;
            mem16[row * 64 + lane] = h;
        }
        float dot = m.x * k4.x + m.y * k4.y + m.z * k4.z + m.w * k4.w;
        float ssq = m.x * m.x + m.y * m.y + m.z * m.z + m.w * m.w;
        dot = wave_reduce_sum(dot);
        ssq = wave_reduce_sum(ssq);
        if (lane == 0) {
            float t = expf(beta * dot * inv_kn / sqrtf(ssq));
            exp_t[row] = t;
            local += t;
        }
    }
    __shared__ float sb[4];
    if (lane == 0) sb[wv] = local;
    __syncthreads();
    if (tid == 0) p1[blockIdx.x] = (sb[0] + sb[1]) + (sb[2] + sb[3]);
}

// ---- kernel 2 (fused): S1 = sum(p1); wg on-the-fly; circular shift; pow; partials -> p2
__global__ __launch_bounds__(256) void k_shift_pow(const float* __restrict__ exp_t,
                                                   const float* __restrict__ w_prev,
                                                   const float* __restrict__ p1,
                                                   const float* __restrict__ gate_p,
                                                   const float* __restrict__ shift,
                                                   const float* __restrict__ gamma_p,
                                                   float* __restrict__ wlp,
                                                   float* __restrict__ p2) {
    __shared__ float red[256];
    const int tid = threadIdx.x;
    float s = 0.0f;
#pragma unroll
    for (int k = 0; k < 8; ++k) s += p1[tid + 256 * k];
    red[tid] = s;
    __syncthreads();
    for (int st = 128; st > 0; st >>= 1) {
        if (tid < st) red[tid] += red[tid + st];
        __syncthreads();
    }
    const float invS1 = 1.0f / red[0];
    __syncthreads();

    const float g  = gate_p[0];
    const float s0 = clamp01f(shift[0]);
    const float s1 = clamp01f(shift[1]);
    const float s2 = clamp01f(shift[2]);
    const float gmm = gamma_p[0];
    const int i = blockIdx.x * 256 + tid;

    const int ip = (i + 1) & (NN - 1);
    const int im = (i + NN - 1) & (NN - 1);
    const float wg_p = g * (exp_t[ip] * invS1) + (1.0f - g) * clamp01f(w_prev[ip]);
    const float wg_c = g * (exp_t[i]  * invS1) + (1.0f - g) * clamp01f(w_prev[i]);
    const float wg_m = g * (exp_t[im] * invS1) + (1.0f - g) * clamp01f(w_prev[im]);
    const float wl = s0 * wg_p + s1 * wg_c + s2 * wg_m;
    const float v  = powf(wl, gmm);
    wlp[i] = v;

    red[tid] = v;
    __syncthreads();
    for (int st = 128; st > 0; st >>= 1) {
        if (tid < st) red[tid] += red[tid + st];
        __syncthreads();
    }
    if (tid == 0) p2[blockIdx.x] = red[0];
}

// ---- kernel 3 (fused): S2; w out; erase+add; r partials. Block b owns 64 consecutive rows.
//      Reads fp16 shadow copy (halved read traffic, LLC-friendly) when available.
__global__ __launch_bounds__(256) void k_update(const float* __restrict__ mem,
                                                const f16x4* __restrict__ mem16,
                                                int use16,
                                                const float* __restrict__ wlp,
                                                const float* __restrict__ p2,
                                                const float* __restrict__ e,
                                                const float* __restrict__ a,
                                                float* __restrict__ out_mem,
                                                float* __restrict__ out_w,
                                                float* __restrict__ rp) {
    __shared__ float lds[4 * 256];
    const int tid  = threadIdx.x;
    const int lane = tid & 63;
    const int wv   = tid >> 6;

    // S2 reduction (every block, 2 KB L2-hit)
    lds[tid] = p2[tid] + p2[tid + 256];
    __syncthreads();
    for (int st = 128; st > 0; st >>= 1) {
        if (tid < st) lds[tid] += lds[tid + st];
        __syncthreads();
    }
    const float invS2 = 1.0f / lds[0];
    __syncthreads();

    const int b0 = blockIdx.x * 64;
    if (tid < 64) out_w[b0 + tid] = wlp[b0 + tid] * invS2;

    float4 e4 = reinterpret_cast<const float4*>(e)[lane];
    e4.x = clamp01f(e4.x); e4.y = clamp01f(e4.y);
    e4.z = clamp01f(e4.z); e4.w = clamp01f(e4.w);
    float4 a4 = reinterpret_cast<const float4*>(a)[lane];
    a4.x = clamp01f(a4.x); a4.y = clamp01f(a4.y);
    a4.z = clamp01f(a4.z); a4.w = clamp01f(a4.w);

    const int r0 = b0 + wv * 16;
    float wl16 = (lane < 16) ? wlp[r0 + lane] : 0.0f;

    float4 racc = make_float4(0.0f, 0.0f, 0.0f, 0.0f);
#pragma unroll
    for (int k = 0; k < 16; ++k) {
        const float wr = clamp01f(__shfl(wl16, k) * invS2);
        const int row = r0 + k;
        float4 m;
        if (use16) {
            f16x4 h = mem16[row * 64 + lane];
            m.x = (float)h.x; m.y = (float)h.y; m.z = (float)h.z; m.w = (float)h.w;
        } else {
            m = reinterpret_cast<const float4*>(mem)[row * 64 + lane];
        }
        f32x4 nm;
        nm.x = m.x * (1.0f - wr * e4.x) + wr * a4.x;
        nm.y = m.y * (1.0f - wr * e4.y) + wr * a4.y;
        nm.z = m.z * (1.0f - wr * e4.z) + wr * a4.z;
        nm.w = m.w * (1.0f - wr * e4.w) + wr * a4.w;
        __builtin_nontemporal_store(nm, reinterpret_cast<f32x4*>(out_mem) + row * 64 + lane);
        racc.x += wr * m.x;
        racc.y += wr * m.y;
        racc.z += wr * m.z;
        racc.w += wr * m.w;
    }
    reinterpret_cast<float4*>(lds)[wv * 64 + lane] = racc;
    __syncthreads();
    const float s = lds[0 * 256 + tid] + lds[1 * 256 + tid] + lds[2 * 256 + tid] + lds[3 * 256 + tid];
    rp[blockIdx.x * 256 + tid] = s;
}

// ---- r reduction stage 1: 32 blocks, block b sums partial rows [b*64, b*64+64)
__global__ __launch_bounds__(256) void k_rstage(const float* __restrict__ rp,
                                                float* __restrict__ rp2) {
    const int tid = threadIdx.x;
    const int b   = blockIdx.x;
    float s = 0.0f;
    for (int k = 0; k < 64; ++k) s += rp[(b * 64 + k) * 256 + tid];
    rp2[b * 256 + tid] = s;
}

// ---- r reduction stage 2: final r[256]
__global__ __launch_bounds__(256) void k_rfinal(const float* __restrict__ rp2,
                                                float* __restrict__ out_r) {
    const int tid = threadIdx.x;
    float s = 0.0f;
    for (int b = 0; b < 32; ++b) s += rp2[b * 256 + tid];
    out_r[tid] = s;
}

extern "C" void kernel_launch(void* const* d_in, const int* in_sizes, int n_in,
                              void* d_out, int out_size, void* d_ws, size_t ws_size,
                              hipStream_t stream) {
    const float* mem    = (const float*)d_in[0];
    const float* key    = (const float*)d_in[1];
    const float* beta_p = (const float*)d_in[2];
    const float* gamma_p= (const float*)d_in[3];
    const float* gate_p = (const float*)d_in[4];
    const float* shift  = (const float*)d_in[5];
    const float* w_prev = (const float*)d_in[6];
    const float* e      = (const float*)d_in[7];
    const float* a      = (const float*)d_in[8];

    float* out   = (float*)d_out;
    float* out_r = out;                        // [256]
    float* out_m = out + WW;                   // [131072*256]
    float* out_w = out + WW + (size_t)NN * WW; // [131072]

    // workspace layout: [mem16 (optional, 67MB)] [exp_t N] [wlp N] [p1 2048] [p2 512] [rp 2048*256] [rp2 32*256]
    const size_t mem16_bytes = (size_t)NN * WW * 2;       // 67,108,864
    const size_t tail_bytes  = ((size_t)2 * NN + 2048 + 512 + 2048 * 256 + 32 * 256) * 4;
    const int use16 = (ws_size >= mem16_bytes + tail_bytes) ? 1 : 0;

    char* wsb = (char*)d_ws;
    f16x4* mem16 = (f16x4*)wsb;
    float* ws = (float*)(wsb + (use16 ? mem16_bytes : 0));
    float* exp_t = ws;                         // N
    float* wlp   = ws + NN;                    // N
    float* p1    = ws + 2 * NN;                // 2048
    float* p2    = p1 + 2048;                  // 512
    float* rp    = p2 + 512;                   // 2048*256
    float* rp2   = rp + 2048 * 256;            // 32*256

    k_content<<<2048, 256, 0, stream>>>(mem, key, beta_p, exp_t, p1, mem16, use16);
    k_shift_pow<<<512, 256, 0, stream>>>(exp_t, w_prev, p1, gate_p, shift, gamma_p, wlp, p2);
    k_update<<<2048, 256, 0, stream>>>(mem, mem16, use16, wlp, p2, e, a, out_m, out_w, rp);
    k_rstage<<<32, 256, 0, stream>>>(rp, rp2);
    k_rfinal<<<1, 256, 0, stream>>>(rp2, out_r);
}